// Round 7
// baseline (30.441 us; speedup 1.0000x reference)
//
#include <hip/hip_runtime.h>

#define T_DIM 1024
#define B_DIM 32
#define C_DIM 512
#define PROWS 16   // p-rows per block

typedef float f32x4 __attribute__((ext_vector_type(4)));

// One block = one batch b, 16 consecutive p-rows.
//   A: labels load + block-scan compaction
//   B: means of labeled video rows (L2/L3-served)
//   C: 8 audio row-loads PINNED via asm volatile global_load_dwordx4
//      (compiler cannot sink/rotate them); windowed product runs under them
//   D: barrier, vmcnt(0) binding all 8 values, mul + store burst
__global__ __launch_bounds__(256) void k_fused(const float* __restrict__ video,
                                               const float* __restrict__ audio,
                                               const int* __restrict__ labels,
                                               float* __restrict__ out) {
    int b     = blockIdx.y;
    int pBase = blockIdx.x * PROWS;
    int tid   = threadIdx.x;
    int lane  = tid & 63;
    int wave  = tid >> 6;
    __shared__ float vm[T_DIM];
    __shared__ int   pos[T_DIM];
    __shared__ int   waveTot[4];
    __shared__ float sscale[PROWS];

    // streaming geometry: thread handles rows k = 2*i + half, i = 0..7
    int half = tid >> 7;
    int c4   = tid & 127;
    const int rstep = 2 * B_DIM * (C_DIM / 4);   // float4 units between rows
    int base0 = ((pBase + half) * B_DIM + b) * (C_DIM / 4) + c4;

    // ---- phase A: labels + block scan ----
    int4 lv = *(const int4*)(labels + b * T_DIM + tid * 4);
    int p0 = tid * 4;
    int f0 = (lv.x == 1), f1 = (lv.y == 1), f2 = (lv.z == 1), f3 = (lv.w == 1);
    int cnt = f0 + f1 + f2 + f3;

    int incl = cnt;
    #pragma unroll
    for (int off = 1; off < 64; off <<= 1) {
        int n = __shfl_up(incl, off);
        if (lane >= off) incl += n;
    }
    if (lane == 63) waveTot[wave] = incl;
    __syncthreads();

    int waveOff = 0;
    for (int w = 0; w < wave; ++w) waveOff += waveTot[w];
    int t = waveTot[0] + waveTot[1] + waveTot[2] + waveTot[3];
    int r = waveOff + incl - cnt;

    if (f0) pos[r++] = p0 + 0;
    if (f1) pos[r++] = p0 + 1;
    if (f2) pos[r++] = p0 + 2;
    if (f3) pos[r++] = p0 + 3;
    __syncthreads();

    // ---- phase B: means of labeled rows, 2 rows per wave-iteration ----
    for (int rr = wave; rr < t; rr += 8) {
        const float* srcA = video + (size_t)pos[rr] * (B_DIM * C_DIM) + b * C_DIM;
        int rr2 = rr + 4;
        bool has2 = rr2 < t;
        const float* srcB = has2 ? video + (size_t)pos[rr2] * (B_DIM * C_DIM) + b * C_DIM
                                 : srcA;
        float4 va0 = *(const float4*)(srcA + lane * 4);
        float4 va1 = *(const float4*)(srcA + 256 + lane * 4);
        float4 vb0 = *(const float4*)(srcB + lane * 4);
        float4 vb1 = *(const float4*)(srcB + 256 + lane * 4);
        float sA = va0.x + va0.y + va0.z + va0.w + va1.x + va1.y + va1.z + va1.w;
        float sB = vb0.x + vb0.y + vb0.z + vb0.w + vb1.x + vb1.y + vb1.z + vb1.w;
        #pragma unroll
        for (int off = 32; off; off >>= 1) {
            sA += __shfl_xor(sA, off);
            sB += __shfl_xor(sB, off);
        }
        if (lane == 0) {
            vm[rr] = sA * (1.0f / C_DIM);
            if (has2) vm[rr2] = sB * (1.0f / C_DIM);
        }
    }
    __syncthreads();

    // ---- phase C: pinned audio loads (cannot be sunk by the compiler) ----
    unsigned voff = (unsigned)base0 * 16u;      // per-thread byte offset
    f32x4 a0, a1, a2, a3, a4, a5, a6, a7;
    asm volatile("global_load_dwordx4 %0, %1, %2" : "=v"(a0) : "v"(voff), "s"(audio + 0 * (size_t)rstep * 4));
    asm volatile("global_load_dwordx4 %0, %1, %2" : "=v"(a1) : "v"(voff), "s"(audio + 1 * (size_t)rstep * 4));
    asm volatile("global_load_dwordx4 %0, %1, %2" : "=v"(a2) : "v"(voff), "s"(audio + 2 * (size_t)rstep * 4));
    asm volatile("global_load_dwordx4 %0, %1, %2" : "=v"(a3) : "v"(voff), "s"(audio + 3 * (size_t)rstep * 4));
    asm volatile("global_load_dwordx4 %0, %1, %2" : "=v"(a4) : "v"(voff), "s"(audio + 4 * (size_t)rstep * 4));
    asm volatile("global_load_dwordx4 %0, %1, %2" : "=v"(a5) : "v"(voff), "s"(audio + 5 * (size_t)rstep * 4));
    asm volatile("global_load_dwordx4 %0, %1, %2" : "=v"(a6) : "v"(voff), "s"(audio + 6 * (size_t)rstep * 4));
    asm volatile("global_load_dwordx4 %0, %1, %2" : "=v"(a7) : "v"(voff), "s"(audio + 7 * (size_t)rstep * 4));

    // windowed product runs while the 8 loads are in flight
    if (tid < PROWS) {
        int p  = pBase + tid;
        int lo = p - (T_DIM - t); if (lo < 0) lo = 0;
        int hi = p < (t - 1) ? p : (t - 1);
        float s = 1.0f;
        for (int m = lo; m <= hi; ++m) s *= vm[m];
        sscale[tid] = s;
    }
    __syncthreads();

    // ---- phase D: bind the loaded values behind vmcnt(0), mul, store ----
    asm volatile("s_waitcnt vmcnt(0)"
                 : "+v"(a0), "+v"(a1), "+v"(a2), "+v"(a3),
                   "+v"(a4), "+v"(a5), "+v"(a6), "+v"(a7));

    float s0 = sscale[0 + half],  s1 = sscale[2 + half];
    float s2 = sscale[4 + half],  s3 = sscale[6 + half];
    float s4 = sscale[8 + half],  s5 = sscale[10 + half];
    float s6 = sscale[12 + half], s7 = sscale[14 + half];

    f32x4* aout = (f32x4*)out;
    aout[base0 + 0 * rstep] = a0 * s0;
    aout[base0 + 1 * rstep] = a1 * s1;
    aout[base0 + 2 * rstep] = a2 * s2;
    aout[base0 + 3 * rstep] = a3 * s3;
    aout[base0 + 4 * rstep] = a4 * s4;
    aout[base0 + 5 * rstep] = a5 * s5;
    aout[base0 + 6 * rstep] = a6 * s6;
    aout[base0 + 7 * rstep] = a7 * s7;
}

extern "C" void kernel_launch(void* const* d_in, const int* in_sizes, int n_in,
                              void* d_out, int out_size, void* d_ws, size_t ws_size,
                              hipStream_t stream) {
    const float* video  = (const float*)d_in[0];
    const float* audio  = (const float*)d_in[1];
    const int*   labels = (const int*)d_in[2];
    float* out = (float*)d_out;

    dim3 grid(T_DIM / PROWS, B_DIM);
    k_fused<<<grid, 256, 0, stream>>>(video, audio, labels, out);
}